// Round 7
// baseline (105.482 us; speedup 1.0000x reference)
//
#include <hip/hip_runtime.h>

// Problem constants (fixed by the reference: N=8192, F=256).
#define NN 8192
#define FF 256

typedef float floatx4 __attribute__((ext_vector_type(4)));

// Kernel 1: per-row dual dot product.
// One 64-lane wave per row; F=256 = 64 lanes x float4.
__global__ void row_scores_kernel(const float* __restrict__ x,
                                  const float* __restrict__ W,
                                  const float* __restrict__ b,
                                  float* __restrict__ left,
                                  float* __restrict__ right) {
    const int row  = (int)((blockIdx.x * blockDim.x + threadIdx.x) >> 6);
    const int lane = (int)(threadIdx.x & 63);
    if (row >= NN) return;

    const floatx4 xv = reinterpret_cast<const floatx4*>(x + (size_t)row * FF)[lane];
    const floatx4 wl = reinterpret_cast<const floatx4*>(W)[lane];
    const floatx4 wr = reinterpret_cast<const floatx4*>(W + FF)[lane];

    float l = xv.x * wl.x + xv.y * wl.y + xv.z * wl.z + xv.w * wl.w;
    float r = xv.x * wr.x + xv.y * wr.y + xv.z * wr.z + xv.w * wr.w;

    #pragma unroll
    for (int off = 32; off; off >>= 1) {
        l += __shfl_down(l, off, 64);
        r += __shfl_down(r, off, 64);
    }
    if (lane == 0) {
        left[row]  = l + b[0];
        right[row] = r;
    }
}

__device__ __forceinline__ float sigmoid_fast(float s) {
    return __builtin_amdgcn_rcpf(1.0f + __expf(-s));
}

// System-scope nontemporal store: sc0 sc1 nt on MUBUF-class global store.
// Goal: keep the 256 MB write stream from allocating/evicting in the
// Infinity Cache so adj (256 MB, exactly MALL-sized) stays resident
// across graph replays (steady-state FETCH_SIZE was already only ~52%
// of adj with plain NT stores).
__device__ __forceinline__ void store_nt_bypass(floatx4* p, floatx4 v) {
    asm volatile("global_store_dwordx4 %0, %1, off sc0 sc1 nt"
                 :: "v"(p), "v"(v) : "memory");
}

// Kernel 2: out[i,j] = adj[i,j] * sigmoid(left[i] + right[j])
// R5 structure (best: 100.5 us, VGPR 48): block b owns rows [4b, 4b+4),
// left -> SGPR scalar loads, right quads hoisted to 32 VGPRs and reused
// across the 4 rows, row loop NOT unrolled to bound VGPRs -> 8 waves/SIMD.
#define ROWS_PER_BLOCK 4
#define Q_PER_ROW (NN / 4 / 256)   // 8 float4-quads per thread per row

__global__ __launch_bounds__(256) void att_kernel(const float* __restrict__ adj,
                                                  const float* __restrict__ left,
                                                  const float* __restrict__ right,
                                                  float* __restrict__ out) {
    const unsigned t  = threadIdx.x;
    const unsigned r0 = blockIdx.x * ROWS_PER_BLOCK;

    const floatx4* __restrict__ adj4   = reinterpret_cast<const floatx4*>(adj);
    const floatx4* __restrict__ right4 = reinterpret_cast<const floatx4*>(right);
    floatx4* __restrict__ out4         = reinterpret_cast<floatx4*>(out);

    floatx4 rq[Q_PER_ROW];
    #pragma unroll
    for (int q = 0; q < Q_PER_ROW; ++q)
        rq[q] = right4[t + (unsigned)q * 256u];

    float lrow[ROWS_PER_BLOCK];
    #pragma unroll
    for (int k = 0; k < ROWS_PER_BLOCK; ++k)
        lrow[k] = left[r0 + k];

    #pragma unroll 1
    for (int k = 0; k < ROWS_PER_BLOCK; ++k) {
        const unsigned rowbase = (r0 + k) * (NN / 4);
        const float li = lrow[k];
        #pragma unroll
        for (int q = 0; q < Q_PER_ROW; ++q) {
            const unsigned idx = rowbase + t + (unsigned)q * 256u;
            const floatx4 a = adj4[idx];
            floatx4 o;
            o.x = a.x * sigmoid_fast(li + rq[q].x);
            o.y = a.y * sigmoid_fast(li + rq[q].y);
            o.z = a.z * sigmoid_fast(li + rq[q].z);
            o.w = a.w * sigmoid_fast(li + rq[q].w);
            store_nt_bypass(&out4[idx], o);
        }
    }
}

extern "C" void kernel_launch(void* const* d_in, const int* in_sizes, int n_in,
                              void* d_out, int out_size, void* d_ws, size_t ws_size,
                              hipStream_t stream) {
    const float* x   = (const float*)d_in[0];   // [N, F]
    const float* adj = (const float*)d_in[1];   // [N, N]
    const float* W   = (const float*)d_in[2];   // [2F, 1]
    const float* b   = (const float*)d_in[3];   // [1]
    float* out = (float*)d_out;                 // [N, N]

    float* left  = (float*)d_ws;                // N floats
    float* right = left + NN;                   // N floats

    row_scores_kernel<<<dim3((NN * 64) / 256), dim3(256), 0, stream>>>(x, W, b, left, right);
    att_kernel<<<dim3(NN / ROWS_PER_BLOCK), dim3(256), 0, stream>>>(adj, left, right, out);
}

// Round 8
// 101.847 us; speedup vs baseline: 1.0357x; 1.0357x over previous
//
#include <hip/hip_runtime.h>

// Problem constants (fixed by the reference: N=8192, F=256).
#define NN 8192
#define FF 256

typedef float floatx4 __attribute__((ext_vector_type(4)));

// Kernel 1: per-row dual dot product.
// One 64-lane wave per row; F=256 = 64 lanes x float4.
__global__ void row_scores_kernel(const float* __restrict__ x,
                                  const float* __restrict__ W,
                                  const float* __restrict__ b,
                                  float* __restrict__ left,
                                  float* __restrict__ right) {
    const int row  = (int)((blockIdx.x * blockDim.x + threadIdx.x) >> 6);
    const int lane = (int)(threadIdx.x & 63);
    if (row >= NN) return;

    const floatx4 xv = reinterpret_cast<const floatx4*>(x + (size_t)row * FF)[lane];
    const floatx4 wl = reinterpret_cast<const floatx4*>(W)[lane];
    const floatx4 wr = reinterpret_cast<const floatx4*>(W + FF)[lane];

    float l = xv.x * wl.x + xv.y * wl.y + xv.z * wl.z + xv.w * wl.w;
    float r = xv.x * wr.x + xv.y * wr.y + xv.z * wr.z + xv.w * wr.w;

    #pragma unroll
    for (int off = 32; off; off >>= 1) {
        l += __shfl_down(l, off, 64);
        r += __shfl_down(r, off, 64);
    }
    if (lane == 0) {
        left[row]  = l + b[0];
        right[row] = r;
    }
}

__device__ __forceinline__ float sigmoid_fast(float s) {
    return __builtin_amdgcn_rcpf(1.0f + __expf(-s));
}

// Kernel 2: out[i,j] = adj[i,j] * sigmoid(left[i] + right[j])
// Best-measured structure (R5, 100.5 us): block b owns rows [4b, 4b+4).
//  - left[4b..4b+3] -> block-uniform SGPR scalar loads.
//  - right quads hoisted to 32 VGPRs once, reused across the 4 rows.
//  - row loop NOT unrolled (#pragma unroll 1): bounds VGPRs to 48 ->
//    8 waves/SIMD; TLP supplies the memory parallelism. (Deeper ILP /
//    pipelining variants measured SLOWER: R3 117.4, R6 104.7.)
//  - plain nontemporal store for the write-once out stream. (System-scope
//    sc0 sc1 nt store measured null on FETCH and -5% on time: the MALL is
//    memory-side; write traffic transits it regardless.)
#define ROWS_PER_BLOCK 4
#define Q_PER_ROW (NN / 4 / 256)   // 8 float4-quads per thread per row

__global__ __launch_bounds__(256) void att_kernel(const float* __restrict__ adj,
                                                  const float* __restrict__ left,
                                                  const float* __restrict__ right,
                                                  float* __restrict__ out) {
    const unsigned t  = threadIdx.x;
    const unsigned r0 = blockIdx.x * ROWS_PER_BLOCK;

    const floatx4* __restrict__ adj4   = reinterpret_cast<const floatx4*>(adj);
    const floatx4* __restrict__ right4 = reinterpret_cast<const floatx4*>(right);
    floatx4* __restrict__ out4         = reinterpret_cast<floatx4*>(out);

    floatx4 rq[Q_PER_ROW];
    #pragma unroll
    for (int q = 0; q < Q_PER_ROW; ++q)
        rq[q] = right4[t + (unsigned)q * 256u];

    float lrow[ROWS_PER_BLOCK];
    #pragma unroll
    for (int k = 0; k < ROWS_PER_BLOCK; ++k)
        lrow[k] = left[r0 + k];

    #pragma unroll 1
    for (int k = 0; k < ROWS_PER_BLOCK; ++k) {
        const unsigned rowbase = (r0 + k) * (NN / 4);
        const float li = lrow[k];
        #pragma unroll
        for (int q = 0; q < Q_PER_ROW; ++q) {
            const unsigned idx = rowbase + t + (unsigned)q * 256u;
            const floatx4 a = adj4[idx];
            floatx4 o;
            o.x = a.x * sigmoid_fast(li + rq[q].x);
            o.y = a.y * sigmoid_fast(li + rq[q].y);
            o.z = a.z * sigmoid_fast(li + rq[q].z);
            o.w = a.w * sigmoid_fast(li + rq[q].w);
            __builtin_nontemporal_store(o, &out4[idx]);
        }
    }
}

extern "C" void kernel_launch(void* const* d_in, const int* in_sizes, int n_in,
                              void* d_out, int out_size, void* d_ws, size_t ws_size,
                              hipStream_t stream) {
    const float* x   = (const float*)d_in[0];   // [N, F]
    const float* adj = (const float*)d_in[1];   // [N, N]
    const float* W   = (const float*)d_in[2];   // [2F, 1]
    const float* b   = (const float*)d_in[3];   // [1]
    float* out = (float*)d_out;                 // [N, N]

    float* left  = (float*)d_ws;                // N floats
    float* right = left + NN;                   // N floats

    row_scores_kernel<<<dim3((NN * 64) / 256), dim3(256), 0, stream>>>(x, W, b, left, right);
    att_kernel<<<dim3(NN / ROWS_PER_BLOCK), dim3(256), 0, stream>>>(adj, left, right, out);
}